// Round 2
// baseline (505.121 us; speedup 1.0000x reference)
//
#include <hip/hip_runtime.h>
#include <math.h>

// Problem constants (from reference)
#define B 2
#define S 2048
#define DIN 512
#define E 512
#define H 8
#define HD 64
#define HALF 128          // WIN/2
#define N3E (3*E)         // 1536
#define M (B*S)           // 4096
#define TM 8              // rows per block in the GEMM stages

// ---------------------------------------------------------------------------
// Stage 1: qkv[m, n] = x[m, :] . w_qkv[n, :] + b_qkv[n]   (fp32)
// Grid: M/TM blocks x 256 threads. TM x-rows staged in LDS; each thread
// walks n with stride 256, streaming w rows as float4 (all-lane-same LDS
// reads of xs broadcast conflict-free).
// ---------------------------------------------------------------------------
__global__ __launch_bounds__(256) void qkv_kernel(
    const float* __restrict__ x, const float* __restrict__ w,
    const float* __restrict__ bias, float* __restrict__ qkv)
{
    __shared__ float xs[TM][DIN];
    const int m0 = blockIdx.x * TM;
    const int t = threadIdx.x;

    // TM*DIN = 4096 floats = 1024 float4; 4 per thread
    const float4* xin = (const float4*)(x + (size_t)m0 * DIN);
    float4* xsv = (float4*)&xs[0][0];
    #pragma unroll
    for (int r = 0; r < 4; ++r) xsv[t + 256 * r] = xin[t + 256 * r];
    __syncthreads();

    for (int n = t; n < N3E; n += 256) {
        const float4* wrow = (const float4*)(w + (size_t)n * DIN);
        float acc[TM];
        #pragma unroll
        for (int r = 0; r < TM; ++r) acc[r] = 0.f;

        for (int k4 = 0; k4 < DIN / 4; ++k4) {
            float4 wv = wrow[k4];
            const int k = k4 * 4;
            #pragma unroll
            for (int r = 0; r < TM; ++r) {
                acc[r] = fmaf(xs[r][k + 0], wv.x, acc[r]);
                acc[r] = fmaf(xs[r][k + 1], wv.y, acc[r]);
                acc[r] = fmaf(xs[r][k + 2], wv.z, acc[r]);
                acc[r] = fmaf(xs[r][k + 3], wv.w, acc[r]);
            }
        }
        const float bv = bias[n];
        #pragma unroll
        for (int r = 0; r < TM; ++r)
            qkv[(size_t)(m0 + r) * N3E + n] = acc[r] + bv;
    }
}

// ---------------------------------------------------------------------------
// Stage 2: banded attention. One wave (64 threads) per (b, h, i).
// qkv layout per row: [h*192 + 0..63]=q, [+64..127]=k, [+128..191]=v.
// Band: |i-j| <= 128. Logit = -inf if off-band, key/query padded, or
// score exactly 0.0 (reference's `scores == 0.0 -> -inf`).
// Fully-masked row -> output 0.
// ---------------------------------------------------------------------------
__global__ __launch_bounds__(64) void attn_kernel(
    const float* __restrict__ qkv, const int* __restrict__ mask,
    float* __restrict__ vals)
{
    const int i  = blockIdx.x & (S - 1);
    const int bh = blockIdx.x >> 11;           // S = 2048
    const int h  = bh & (H - 1);
    const int b  = bh >> 3;
    const int lane = threadIdx.x;

    float* valrow = vals + ((size_t)(b * S + i) * E + h * HD);

    if (mask[b * S + i] == 0) {                // padded query -> zeros
        valrow[lane] = 0.f;
        return;
    }

    __shared__ float qs[HD];
    __shared__ float sc[2 * HALF + 1];

    const float* qrow = qkv + ((size_t)(b * S + i) * N3E + h * 3 * HD);
    qs[lane] = qrow[lane];
    __syncthreads();

    const int jlo = max(0, i - HALF);
    const int jhi = min(S - 1, i + HALF);
    const int cnt = jhi - jlo + 1;             // 129..257

    float lmax = -INFINITY;
    for (int jj = lane; jj < cnt; jj += 64) {
        const int j = jlo + jj;
        float logit;
        if (mask[b * S + j] == 0) {
            logit = -INFINITY;
        } else {
            const float4* krow = (const float4*)(qkv + ((size_t)(b * S + j) * N3E + h * 3 * HD + HD));
            float acc = 0.f;
            #pragma unroll
            for (int d4 = 0; d4 < HD / 4; ++d4) {
                float4 kv = krow[d4];
                acc = fmaf(qs[d4 * 4 + 0], kv.x, acc);
                acc = fmaf(qs[d4 * 4 + 1], kv.y, acc);
                acc = fmaf(qs[d4 * 4 + 2], kv.z, acc);
                acc = fmaf(qs[d4 * 4 + 3], kv.w, acc);
            }
            acc *= 0.125f;                     // 1/sqrt(64)
            logit = (acc == 0.0f) ? -INFINITY : acc;
        }
        sc[jj] = logit;
        lmax = fmaxf(lmax, logit);
    }
    #pragma unroll
    for (int off = 32; off; off >>= 1) lmax = fmaxf(lmax, __shfl_down(lmax, off));
    lmax = __shfl(lmax, 0);
    __syncthreads();

    float lsum = 0.f;
    if (lmax > -INFINITY) {
        for (int jj = lane; jj < cnt; jj += 64) {
            float p = __expf(sc[jj] - lmax);
            sc[jj] = p;
            lsum += p;
        }
    }
    #pragma unroll
    for (int off = 32; off; off >>= 1) lsum += __shfl_down(lsum, off);
    lsum = __shfl(lsum, 0);
    __syncthreads();

    float out = 0.f;
    if (lmax > -INFINITY && lsum > 0.f) {
        const float inv = 1.f / lsum;
        const float* vbase = qkv + ((size_t)(b * S + jlo) * N3E + h * 3 * HD + 2 * HD);
        for (int jj = 0; jj < cnt; ++jj) {
            out = fmaf(sc[jj], vbase[(size_t)jj * N3E + lane], out);
        }
        out *= inv;
    }
    valrow[lane] = out;
}

// ---------------------------------------------------------------------------
// Stage 3: out[m, e] = vals[m, :] . w_o[e, :] + b_o[e]   (fp32 out)
// Same tiling as stage 1 (TM rows/block).
// ---------------------------------------------------------------------------
__global__ __launch_bounds__(256) void outproj_kernel(
    const float* __restrict__ vals, const float* __restrict__ wo,
    const float* __restrict__ bo, float* __restrict__ out)
{
    __shared__ float vs[TM][E];
    const int m0 = blockIdx.x * TM;
    const int t = threadIdx.x;

    const float4* vin = (const float4*)(vals + (size_t)m0 * E);
    float4* vsv = (float4*)&vs[0][0];
    #pragma unroll
    for (int r = 0; r < 4; ++r) vsv[t + 256 * r] = vin[t + 256 * r];
    __syncthreads();

    for (int n = t; n < E; n += 256) {
        const float4* wrow = (const float4*)(wo + (size_t)n * E);
        float acc[TM];
        #pragma unroll
        for (int r = 0; r < TM; ++r) acc[r] = 0.f;

        for (int k4 = 0; k4 < E / 4; ++k4) {
            float4 wv = wrow[k4];
            const int k = k4 * 4;
            #pragma unroll
            for (int r = 0; r < TM; ++r) {
                acc[r] = fmaf(vs[r][k + 0], wv.x, acc[r]);
                acc[r] = fmaf(vs[r][k + 1], wv.y, acc[r]);
                acc[r] = fmaf(vs[r][k + 2], wv.z, acc[r]);
                acc[r] = fmaf(vs[r][k + 3], wv.w, acc[r]);
            }
        }
        const float bv = bo[n];
        #pragma unroll
        for (int r = 0; r < TM; ++r)
            out[(size_t)(m0 + r) * E + n] = acc[r] + bv;
    }
}

extern "C" void kernel_launch(void* const* d_in, const int* in_sizes, int n_in,
                              void* d_out, int out_size, void* d_ws, size_t ws_size,
                              hipStream_t stream)
{
    const float* x     = (const float*)d_in[0];   // [B,S,DIN] fp32
    const int*   pmask = (const int*)d_in[1];     // [B,S] int32
    const float* w_qkv = (const float*)d_in[2];   // [3E,DIN] fp32
    const float* b_qkv = (const float*)d_in[3];   // [3E] fp32
    const float* w_o   = (const float*)d_in[4];   // [E,E] fp32
    const float* b_o   = (const float*)d_in[5];   // [E] fp32
    float* out = (float*)d_out;                   // [B,S,E] fp32

    // workspace layout: qkv fp32 [M,1536] (25 MiB) | vals fp32 [M,512] (8 MiB)
    float* qkv  = (float*)d_ws;
    float* vals = (float*)((char*)d_ws + (size_t)M * N3E * sizeof(float));

    qkv_kernel<<<M / TM, 256, 0, stream>>>(x, w_qkv, b_qkv, qkv);
    attn_kernel<<<B * H * S, 64, 0, stream>>>(qkv, pmask, vals);
    outproj_kernel<<<M / TM, 256, 0, stream>>>(vals, w_o, b_o, out);
}

// Round 3
// 365.447 us; speedup vs baseline: 1.3822x; 1.3822x over previous
//
#include <hip/hip_runtime.h>
#include <math.h>

// Problem constants
#define B 2
#define S 2048
#define DIN 512
#define E 512
#define H 8
#define HD 64
#define HALF 128          // WIN/2
#define N3E 1536
#define M 4096

// ---------------------------------------------------------------------------
// Stage 1: qkv GEMM  C[m,n] = x[m,:].w[n,:] + bias[n], scattered to
//   Q  [m][h][d]            (m = b*S+s)
//   Kt [b][h][d][s]         (transposed for coalesced score pass)
//   Vc [b][h][s][d]         (compact for dense V pass)
// Block tile 128x128, thread tile 8x8, k-chunk 16. Grid (12, 32).
// ---------------------------------------------------------------------------
#define KC 16
#define LDA 132   // 128 + 4 pad: conflict-free transposed stores, 16B-aligned reads

__global__ __launch_bounds__(256) void qkv_kernel(
    const float* __restrict__ x, const float* __restrict__ w,
    const float* __restrict__ bias,
    float* __restrict__ Q, float* __restrict__ Kt, float* __restrict__ Vc)
{
    __shared__ float as[KC][LDA];
    __shared__ float ws[KC][LDA];

    const int n0 = blockIdx.x * 128;
    const int m0 = blockIdx.y * 128;
    const int t  = threadIdx.x;
    const int tx = t & 15, ty = t >> 4;

    float acc[8][8];
    #pragma unroll
    for (int r = 0; r < 8; ++r)
        #pragma unroll
        for (int c = 0; c < 8; ++c) acc[r][c] = 0.f;

    for (int k0 = 0; k0 < DIN; k0 += KC) {
        // stage A (x) and B (w) tiles, k-major with transpose
        #pragma unroll
        for (int l = 0; l < 2; ++l) {
            const int f  = t + l * 256;      // 0..511
            const int mr = f >> 2;           // 0..127
            const int kq = f & 3;            // 0..3
            float4 av = *(const float4*)(x + (size_t)(m0 + mr) * DIN + k0 + kq * 4);
            as[kq * 4 + 0][mr] = av.x; as[kq * 4 + 1][mr] = av.y;
            as[kq * 4 + 2][mr] = av.z; as[kq * 4 + 3][mr] = av.w;
            float4 bv = *(const float4*)(w + (size_t)(n0 + mr) * DIN + k0 + kq * 4);
            ws[kq * 4 + 0][mr] = bv.x; ws[kq * 4 + 1][mr] = bv.y;
            ws[kq * 4 + 2][mr] = bv.z; ws[kq * 4 + 3][mr] = bv.w;
        }
        __syncthreads();

        #pragma unroll
        for (int k = 0; k < KC; ++k) {
            float a[8], b[8];
            *(float4*)&a[0] = *(const float4*)&as[k][ty * 8];
            *(float4*)&a[4] = *(const float4*)&as[k][ty * 8 + 4];
            *(float4*)&b[0] = *(const float4*)&ws[k][tx * 8];
            *(float4*)&b[4] = *(const float4*)&ws[k][tx * 8 + 4];
            #pragma unroll
            for (int r = 0; r < 8; ++r)
                #pragma unroll
                for (int c = 0; c < 8; ++c)
                    acc[r][c] = fmaf(a[r], b[c], acc[r][c]);
        }
        __syncthreads();
    }

    // epilogue: bias + scatter
    #pragma unroll
    for (int c = 0; c < 8; ++c) {
        const int n  = n0 + tx * 8 + c;
        const int h  = n / 192;
        const int rr = n % 192;
        const int wh = rr >> 6;       // 0=q 1=k 2=v
        const int d  = rr & 63;
        const float bv = bias[n];
        #pragma unroll
        for (int r = 0; r < 8; ++r) {
            const int m  = m0 + ty * 8 + r;
            const int b_ = m >> 11;   // S = 2048
            const int s_ = m & 2047;
            const float v = acc[r][c] + bv;
            if (wh == 0)      Q [((size_t)m * H + h) * HD + d] = v;
            else if (wh == 1) Kt[(((size_t)(b_ * H + h)) * HD + d) * S + s_] = v;
            else              Vc[(((size_t)(b_ * H + h)) * S + s_) * HD + d] = v;
        }
    }
}

// ---------------------------------------------------------------------------
// Stage 2: banded attention, one wave per (b, h, i).
// Band |i-j| <= 128; logit -inf if off-band, padded key/query, or score==0.
// Fully-masked row -> 0. K read coalesced via Kt; V read dense via Vc.
// ---------------------------------------------------------------------------
__global__ __launch_bounds__(64) void attn_kernel(
    const float* __restrict__ Q, const float* __restrict__ Kt,
    const float* __restrict__ Vc, const int* __restrict__ mask,
    float* __restrict__ vals)
{
    const int i  = blockIdx.x & (S - 1);
    const int bh = blockIdx.x >> 11;
    const int h  = bh & (H - 1);
    const int b  = bh >> 3;
    const int lane = threadIdx.x;
    const int m  = b * S + i;

    float* valrow = vals + (size_t)m * E + h * HD;

    if (mask[m] == 0) {                  // padded query -> zeros
        valrow[lane] = 0.f;
        return;
    }

    __shared__ float qs[HD];
    __shared__ float sc[2 * HALF + 4];

    qs[lane] = Q[((size_t)m * H + h) * HD + lane];
    __syncthreads();

    const int jlo = max(0, i - HALF);
    const int jhi = min(S - 1, i + HALF);
    const int cnt = jhi - jlo + 1;       // 129..257

    const float* kt = Kt + ((size_t)(b * H + h)) * HD * S;   // + d*S + j

    float lmax = -INFINITY;
    for (int jj0 = 0; jj0 < cnt; jj0 += 64) {
        const int jj = jj0 + lane;
        float logit = -INFINITY;
        if (jj < cnt) {
            const int j = jlo + jj;
            if (mask[b * S + j]) {
                float a0 = 0.f, a1 = 0.f, a2 = 0.f, a3 = 0.f;
                #pragma unroll
                for (int d = 0; d < HD; d += 4) {
                    a0 = fmaf(qs[d + 0], kt[(size_t)(d + 0) * S + j], a0);
                    a1 = fmaf(qs[d + 1], kt[(size_t)(d + 1) * S + j], a1);
                    a2 = fmaf(qs[d + 2], kt[(size_t)(d + 2) * S + j], a2);
                    a3 = fmaf(qs[d + 3], kt[(size_t)(d + 3) * S + j], a3);
                }
                float acc = ((a0 + a1) + (a2 + a3)) * 0.125f;   // 1/sqrt(64)
                logit = (acc == 0.0f) ? -INFINITY : acc;
            }
            sc[jj] = logit;
        }
        lmax = fmaxf(lmax, logit);
    }
    #pragma unroll
    for (int off = 32; off; off >>= 1) lmax = fmaxf(lmax, __shfl_down(lmax, off));
    lmax = __shfl(lmax, 0);
    __syncthreads();

    float lsum = 0.f;
    if (lmax > -INFINITY) {
        for (int jj = lane; jj < cnt; jj += 64) {
            float p = __expf(sc[jj] - lmax);
            sc[jj] = p;
            lsum += p;
        }
    }
    #pragma unroll
    for (int off = 32; off; off >>= 1) lsum += __shfl_down(lsum, off);
    lsum = __shfl(lsum, 0);
    __syncthreads();

    float out = 0.f;
    if (lmax > -INFINITY && lsum > 0.f) {
        const float* vb = Vc + (((size_t)(b * H + h)) * S + jlo) * HD + lane;
        float o0 = 0.f, o1 = 0.f, o2 = 0.f, o3 = 0.f;
        int jj = 0;
        for (; jj + 4 <= cnt; jj += 4) {
            o0 = fmaf(sc[jj + 0], vb[(size_t)(jj + 0) * HD], o0);
            o1 = fmaf(sc[jj + 1], vb[(size_t)(jj + 1) * HD], o1);
            o2 = fmaf(sc[jj + 2], vb[(size_t)(jj + 2) * HD], o2);
            o3 = fmaf(sc[jj + 3], vb[(size_t)(jj + 3) * HD], o3);
        }
        for (; jj < cnt; ++jj) o0 = fmaf(sc[jj], vb[(size_t)jj * HD], o0);
        out = ((o0 + o1) + (o2 + o3)) / lsum;
    }
    valrow[lane] = out;
}

// ---------------------------------------------------------------------------
// Stage 3: out[m,e] = vals[m,:].w_o[e,:] + b_o[e]
// Block tile 64x64, thread tile 4x4, k-chunk 16. Grid (8, 64).
// ---------------------------------------------------------------------------
#define LDA3 68   // 64 + 4 pad

__global__ __launch_bounds__(256) void outproj_kernel(
    const float* __restrict__ vals, const float* __restrict__ wo,
    const float* __restrict__ bo, float* __restrict__ out)
{
    __shared__ float as[KC][LDA3];
    __shared__ float ws[KC][LDA3];

    const int n0 = blockIdx.x * 64;
    const int m0 = blockIdx.y * 64;
    const int t  = threadIdx.x;
    const int tx = t & 15, ty = t >> 4;

    float acc[4][4];
    #pragma unroll
    for (int r = 0; r < 4; ++r)
        #pragma unroll
        for (int c = 0; c < 4; ++c) acc[r][c] = 0.f;

    for (int k0 = 0; k0 < E; k0 += KC) {
        {
            const int f  = t;                // 0..255
            const int mr = f >> 2;           // 0..63
            const int kq = f & 3;
            float4 av = *(const float4*)(vals + (size_t)(m0 + mr) * E + k0 + kq * 4);
            as[kq * 4 + 0][mr] = av.x; as[kq * 4 + 1][mr] = av.y;
            as[kq * 4 + 2][mr] = av.z; as[kq * 4 + 3][mr] = av.w;
            float4 bv = *(const float4*)(wo + (size_t)(n0 + mr) * E + k0 + kq * 4);
            ws[kq * 4 + 0][mr] = bv.x; ws[kq * 4 + 1][mr] = bv.y;
            ws[kq * 4 + 2][mr] = bv.z; ws[kq * 4 + 3][mr] = bv.w;
        }
        __syncthreads();

        #pragma unroll
        for (int k = 0; k < KC; ++k) {
            float a[4], b[4];
            *(float4*)&a[0] = *(const float4*)&as[k][ty * 4];
            *(float4*)&b[0] = *(const float4*)&ws[k][tx * 4];
            #pragma unroll
            for (int r = 0; r < 4; ++r)
                #pragma unroll
                for (int c = 0; c < 4; ++c)
                    acc[r][c] = fmaf(a[r], b[c], acc[r][c]);
        }
        __syncthreads();
    }

    #pragma unroll
    for (int r = 0; r < 4; ++r) {
        const int m = m0 + ty * 4 + r;
        float4 o;
        o.x = acc[r][0] + bo[n0 + tx * 4 + 0];
        o.y = acc[r][1] + bo[n0 + tx * 4 + 1];
        o.z = acc[r][2] + bo[n0 + tx * 4 + 2];
        o.w = acc[r][3] + bo[n0 + tx * 4 + 3];
        *(float4*)(out + (size_t)m * E + n0 + tx * 4) = o;
    }
}

extern "C" void kernel_launch(void* const* d_in, const int* in_sizes, int n_in,
                              void* d_out, int out_size, void* d_ws, size_t ws_size,
                              hipStream_t stream)
{
    const float* x     = (const float*)d_in[0];   // [B,S,DIN] fp32
    const int*   pmask = (const int*)d_in[1];     // [B,S] int32
    const float* w_qkv = (const float*)d_in[2];   // [3E,DIN] fp32
    const float* b_qkv = (const float*)d_in[3];   // [3E] fp32
    const float* w_o   = (const float*)d_in[4];   // [E,E] fp32
    const float* b_o   = (const float*)d_in[5];   // [E] fp32
    float* out = (float*)d_out;                   // [B,S,E] fp32

    // workspace: Q 8MB | Kt 8MB | Vc 8MB | vals 8MB  (each 2,097,152 floats)
    float* Q    = (float*)d_ws;
    float* Kt   = Q  + (size_t)M * E;
    float* Vc   = Kt + (size_t)M * E;
    float* vals = Vc + (size_t)M * E;

    qkv_kernel<<<dim3(N3E / 128, M / 128), 256, 0, stream>>>(x, w_qkv, b_qkv, Q, Kt, Vc);
    attn_kernel<<<B * H * S, 64, 0, stream>>>(Q, Kt, Vc, pmask, vals);
    outproj_kernel<<<dim3(E / 64, M / 64), 256, 0, stream>>>(vals, w_o, b_o, out);
}

// Round 4
// 256.134 us; speedup vs baseline: 1.9721x; 1.4268x over previous
//
#include <hip/hip_runtime.h>
#include <math.h>

// Problem constants
#define B 2
#define S 2048
#define DIN 512
#define E 512
#define H 8
#define HD 64
#define HALF 128          // WIN/2
#define N3E 1536
#define M 4096
#define BK 32

using short8 = __attribute__((ext_vector_type(8))) short;
using f32x4  = __attribute__((ext_vector_type(4))) float;

// fp32 -> bf16 (RNE) bits, and bf16 bits -> fp32
__device__ __forceinline__ unsigned bfhi(float v) {
    union { float f; unsigned u; } c; c.f = v;
    return (c.u + 0x7fffu + ((c.u >> 16) & 1u)) >> 16;
}
__device__ __forceinline__ float bff(unsigned b) {
    union { unsigned u; float f; } c; c.u = b << 16; return c.f;
}

// split one float4 into hi/lo bf16 short4s
__device__ __forceinline__ void split4(const float4& v, short4& hs, short4& ls) {
    unsigned h0 = bfhi(v.x), h1 = bfhi(v.y), h2 = bfhi(v.z), h3 = bfhi(v.w);
    unsigned l0 = bfhi(v.x - bff(h0)), l1 = bfhi(v.y - bff(h1));
    unsigned l2 = bfhi(v.z - bff(h2)), l3 = bfhi(v.w - bff(h3));
    hs.x = (short)h0; hs.y = (short)h1; hs.z = (short)h2; hs.w = (short)h3;
    ls.x = (short)l0; ls.y = (short)l1; ls.z = (short)l2; ls.w = (short)l3;
}

// ---------------------------------------------------------------------------
// Stage 1: qkv GEMM via split-bf16 MFMA. C[m,n] = x[m,:].w[n,:] + bias[n].
// Block 128x128, BK=32, 4 waves in 2x2, each wave 4x4 MFMA tiles of 16x16x32.
// fp32->bf16(hi,lo) conversion fused into LDS staging; 3-term MFMA per tile.
// Scatter: Q[m][h][d], Kt[b][h][d][s], Vc[b][h][s][d].
// ---------------------------------------------------------------------------
__global__ __launch_bounds__(256) void qkv_mfma(
    const float* __restrict__ x, const float* __restrict__ w,
    const float* __restrict__ bias,
    float* __restrict__ Q, float* __restrict__ Kt, float* __restrict__ Vc)
{
    __shared__ __align__(16) short Ah[4][128][8], Al[4][128][8];
    __shared__ __align__(16) short Bh[4][128][8], Bl[4][128][8];

    const int n0 = blockIdx.x * 128;
    const int m0 = blockIdx.y * 128;
    const int t  = threadIdx.x;
    const int wv = t >> 6, ln = t & 63;
    const int waveM = wv >> 1, waveN = wv & 1;
    const int lr = ln & 15;     // row/col within 16-tile
    const int lk = ln >> 4;     // k-block (0..3) -> k = lk*8 + j

    f32x4 acc[4][4] = {};

    for (int k0 = 0; k0 < DIN; k0 += BK) {
        #pragma unroll
        for (int l = 0; l < 4; ++l) {
            const int f   = t + 256 * l;     // 0..1023
            const int row = f >> 3;          // 0..127
            const int k4  = f & 7;           // float4 index within 32
            const int kb  = k4 >> 1, off = (k4 & 1) * 4;
            float4 va = *(const float4*)(x + (size_t)(m0 + row) * DIN + k0 + k4 * 4);
            short4 hs, ls; split4(va, hs, ls);
            *(short4*)&Ah[kb][row][off] = hs;
            *(short4*)&Al[kb][row][off] = ls;
            float4 vb = *(const float4*)(w + (size_t)(n0 + row) * DIN + k0 + k4 * 4);
            split4(vb, hs, ls);
            *(short4*)&Bh[kb][row][off] = hs;
            *(short4*)&Bl[kb][row][off] = ls;
        }
        __syncthreads();

        short8 a_h[4], a_l[4], b_h[4], b_l[4];
        #pragma unroll
        for (int i = 0; i < 4; ++i) {
            a_h[i] = *(const short8*)&Ah[lk][waveM * 64 + i * 16 + lr][0];
            a_l[i] = *(const short8*)&Al[lk][waveM * 64 + i * 16 + lr][0];
            b_h[i] = *(const short8*)&Bh[lk][waveN * 64 + i * 16 + lr][0];
            b_l[i] = *(const short8*)&Bl[lk][waveN * 64 + i * 16 + lr][0];
        }
        #pragma unroll
        for (int i = 0; i < 4; ++i)
            #pragma unroll
            for (int j = 0; j < 4; ++j) {
                acc[i][j] = __builtin_amdgcn_mfma_f32_16x16x32_bf16(a_h[i], b_h[j], acc[i][j], 0, 0, 0);
                acc[i][j] = __builtin_amdgcn_mfma_f32_16x16x32_bf16(a_h[i], b_l[j], acc[i][j], 0, 0, 0);
                acc[i][j] = __builtin_amdgcn_mfma_f32_16x16x32_bf16(a_l[i], b_h[j], acc[i][j], 0, 0, 0);
            }
        __syncthreads();
    }

    // epilogue: bias + scatter (C/D: col = lane&15, row = (lane>>4)*4 + reg)
    #pragma unroll
    for (int j = 0; j < 4; ++j) {
        const int n  = n0 + waveN * 64 + j * 16 + lr;
        const int h  = n / 192;
        const int rr = n % 192;
        const int wh = rr >> 6;     // 0=q 1=k 2=v
        const int d  = rr & 63;
        const float bv = bias[n];
        #pragma unroll
        for (int i = 0; i < 4; ++i) {
            #pragma unroll
            for (int r = 0; r < 4; ++r) {
                const int m  = m0 + waveM * 64 + i * 16 + lk * 4 + r;
                const int b_ = m >> 11;
                const int s_ = m & 2047;
                const float v = acc[i][j][r] + bv;
                if (wh == 0)      Q [((size_t)m * H + h) * HD + d] = v;
                else if (wh == 1) Kt[(((size_t)(b_ * H + h)) * HD + d) * S + s_] = v;
                else              Vc[(((size_t)(b_ * H + h)) * S + s_) * HD + d] = v;
            }
        }
    }
}

// ---------------------------------------------------------------------------
// Stage 2: banded attention. 4 queries per block (one wave each, per-wave LDS
// slices, no barriers). Band |i-j| <= 128; -inf if off-band, padded key/query,
// or score==0 (reference rule). Fully-masked row -> 0.
// ---------------------------------------------------------------------------
__global__ __launch_bounds__(256) void attn_kernel(
    const float* __restrict__ Q, const float* __restrict__ Kt,
    const float* __restrict__ Vc, const int* __restrict__ mask,
    float* __restrict__ vals)
{
    __shared__ float qs[4][HD];
    __shared__ float sc[4][264];

    const int wv   = threadIdx.x >> 6;
    const int lane = threadIdx.x & 63;
    const int gid  = blockIdx.x * 4 + wv;
    const int i  = gid & (S - 1);
    const int bh = gid >> 11;
    const int h  = bh & (H - 1);
    const int b  = bh >> 3;
    const int m  = b * S + i;

    float* valrow = vals + (size_t)m * E + h * HD;
    if (mask[m] == 0) {                 // wave-uniform; no barriers anywhere
        valrow[lane] = 0.f;
        return;
    }

    qs[wv][lane] = Q[((size_t)m * H + h) * HD + lane];
    __asm__ volatile("s_waitcnt lgkmcnt(0)" ::: "memory");

    const int jlo = max(0, i - HALF);
    const int jhi = min(S - 1, i + HALF);
    const int cnt = jhi - jlo + 1;      // 129..257
    const float* kt = Kt + (size_t)(b * H + h) * HD * S;

    float lmax = -INFINITY;
    for (int jj0 = 0; jj0 < cnt; jj0 += 64) {
        const int jj = jj0 + lane;
        float logit = -INFINITY;
        if (jj < cnt) {
            const int j = jlo + jj;
            if (mask[b * S + j]) {
                float a0 = 0.f, a1 = 0.f, a2 = 0.f, a3 = 0.f;
                #pragma unroll
                for (int d = 0; d < HD; d += 4) {
                    a0 = fmaf(qs[wv][d + 0], kt[(size_t)(d + 0) * S + j], a0);
                    a1 = fmaf(qs[wv][d + 1], kt[(size_t)(d + 1) * S + j], a1);
                    a2 = fmaf(qs[wv][d + 2], kt[(size_t)(d + 2) * S + j], a2);
                    a3 = fmaf(qs[wv][d + 3], kt[(size_t)(d + 3) * S + j], a3);
                }
                float acc = ((a0 + a1) + (a2 + a3)) * 0.125f;   // 1/sqrt(64)
                logit = (acc == 0.0f) ? -INFINITY : acc;
            }
            sc[wv][jj] = logit;
        }
        lmax = fmaxf(lmax, logit);
    }
    #pragma unroll
    for (int off = 32; off; off >>= 1) lmax = fmaxf(lmax, __shfl_down(lmax, off));
    lmax = __shfl(lmax, 0);
    __asm__ volatile("s_waitcnt lgkmcnt(0)" ::: "memory");

    float lsum = 0.f;
    if (lmax > -INFINITY) {
        for (int jj = lane; jj < cnt; jj += 64) {
            float p = __expf(sc[wv][jj] - lmax);
            sc[wv][jj] = p;
            lsum += p;
        }
    }
    #pragma unroll
    for (int off = 32; off; off >>= 1) lsum += __shfl_down(lsum, off);
    lsum = __shfl(lsum, 0);
    __asm__ volatile("s_waitcnt lgkmcnt(0)" ::: "memory");

    float out = 0.f;
    if (lmax > -INFINITY && lsum > 0.f) {
        const float* vb = Vc + ((size_t)(b * H + h) * S + jlo) * HD + lane;
        float o0 = 0.f, o1 = 0.f, o2 = 0.f, o3 = 0.f;
        int jj = 0;
        for (; jj + 4 <= cnt; jj += 4) {
            o0 = fmaf(sc[wv][jj + 0], vb[(size_t)(jj + 0) * HD], o0);
            o1 = fmaf(sc[wv][jj + 1], vb[(size_t)(jj + 1) * HD], o1);
            o2 = fmaf(sc[wv][jj + 2], vb[(size_t)(jj + 2) * HD], o2);
            o3 = fmaf(sc[wv][jj + 3], vb[(size_t)(jj + 3) * HD], o3);
        }
        for (; jj < cnt; ++jj) o0 = fmaf(sc[wv][jj], vb[(size_t)jj * HD], o0);
        out = ((o0 + o1) + (o2 + o3)) / lsum;
    }
    valrow[lane] = out;
}

// ---------------------------------------------------------------------------
// Stage 3: out[m,e] = vals[m,:].w_o[e,:] + b_o[e] via split-bf16 MFMA.
// Block 128(M)x64(N), BK=32, 4 waves stacked in M, each wave 2x4 tiles.
// ---------------------------------------------------------------------------
__global__ __launch_bounds__(256) void outproj_mfma(
    const float* __restrict__ vals, const float* __restrict__ wo,
    const float* __restrict__ bo, float* __restrict__ out)
{
    __shared__ __align__(16) short Ah[4][128][8], Al[4][128][8];
    __shared__ __align__(16) short Bh[4][64][8],  Bl[4][64][8];

    const int n0 = blockIdx.x * 64;
    const int m0 = blockIdx.y * 128;
    const int t  = threadIdx.x;
    const int wv = t >> 6, ln = t & 63;
    const int lr = ln & 15;
    const int lk = ln >> 4;

    f32x4 acc[2][4] = {};

    for (int k0 = 0; k0 < E; k0 += BK) {
        #pragma unroll
        for (int l = 0; l < 4; ++l) {
            const int f   = t + 256 * l;
            const int row = f >> 3;
            const int k4  = f & 7;
            const int kb  = k4 >> 1, off = (k4 & 1) * 4;
            float4 va = *(const float4*)(vals + (size_t)(m0 + row) * E + k0 + k4 * 4);
            short4 hs, ls; split4(va, hs, ls);
            *(short4*)&Ah[kb][row][off] = hs;
            *(short4*)&Al[kb][row][off] = ls;
        }
        #pragma unroll
        for (int l = 0; l < 2; ++l) {
            const int f   = t + 256 * l;     // 0..511
            const int row = f >> 3;          // 0..63
            const int k4  = f & 7;
            const int kb  = k4 >> 1, off = (k4 & 1) * 4;
            float4 vb = *(const float4*)(wo + (size_t)(n0 + row) * E + k0 + k4 * 4);
            short4 hs, ls; split4(vb, hs, ls);
            *(short4*)&Bh[kb][row][off] = hs;
            *(short4*)&Bl[kb][row][off] = ls;
        }
        __syncthreads();

        short8 a_h[2], a_l[2], b_h[4], b_l[4];
        #pragma unroll
        for (int i = 0; i < 2; ++i) {
            a_h[i] = *(const short8*)&Ah[lk][wv * 32 + i * 16 + lr][0];
            a_l[i] = *(const short8*)&Al[lk][wv * 32 + i * 16 + lr][0];
        }
        #pragma unroll
        for (int j = 0; j < 4; ++j) {
            b_h[j] = *(const short8*)&Bh[lk][j * 16 + lr][0];
            b_l[j] = *(const short8*)&Bl[lk][j * 16 + lr][0];
        }
        #pragma unroll
        for (int i = 0; i < 2; ++i)
            #pragma unroll
            for (int j = 0; j < 4; ++j) {
                acc[i][j] = __builtin_amdgcn_mfma_f32_16x16x32_bf16(a_h[i], b_h[j], acc[i][j], 0, 0, 0);
                acc[i][j] = __builtin_amdgcn_mfma_f32_16x16x32_bf16(a_h[i], b_l[j], acc[i][j], 0, 0, 0);
                acc[i][j] = __builtin_amdgcn_mfma_f32_16x16x32_bf16(a_l[i], b_h[j], acc[i][j], 0, 0, 0);
            }
        __syncthreads();
    }

    #pragma unroll
    for (int j = 0; j < 4; ++j) {
        const int n = n0 + j * 16 + lr;
        const float bv = bo[n];
        #pragma unroll
        for (int i = 0; i < 2; ++i) {
            #pragma unroll
            for (int r = 0; r < 4; ++r) {
                const int m = m0 + wv * 32 + i * 16 + lk * 4 + r;
                out[(size_t)m * E + n] = acc[i][j][r] + bv;
            }
        }
    }
}

extern "C" void kernel_launch(void* const* d_in, const int* in_sizes, int n_in,
                              void* d_out, int out_size, void* d_ws, size_t ws_size,
                              hipStream_t stream)
{
    const float* x     = (const float*)d_in[0];   // [B,S,DIN] fp32
    const int*   pmask = (const int*)d_in[1];     // [B,S] int32
    const float* w_qkv = (const float*)d_in[2];   // [3E,DIN] fp32
    const float* b_qkv = (const float*)d_in[3];   // [3E] fp32
    const float* w_o   = (const float*)d_in[4];   // [E,E] fp32
    const float* b_o   = (const float*)d_in[5];   // [E] fp32
    float* out = (float*)d_out;                   // [B,S,E] fp32

    // workspace: Q 8MB | Kt 8MB | Vc 8MB | vals 8MB
    float* Q    = (float*)d_ws;
    float* Kt   = Q  + (size_t)M * E;
    float* Vc   = Kt + (size_t)M * E;
    float* vals = Vc + (size_t)M * E;

    qkv_mfma<<<dim3(N3E / 128, M / 128), 256, 0, stream>>>(x, w_qkv, b_qkv, Q, Kt, Vc);
    attn_kernel<<<(B * H * S) / 4, 256, 0, stream>>>(Q, Kt, Vc, pmask, vals);
    outproj_mfma<<<dim3(E / 64, M / 128), 256, 0, stream>>>(vals, w_o, b_o, out);
}